// Round 1
// baseline (12919.414 us; speedup 1.0000x reference)
//
#include <hip/hip_runtime.h>
#include <math.h>

// ---- problem constants -------------------------------------------------
#define L_    7
#define H_    8
#define DF_   980
#define DP_   44
#define DD_   1024
#define HDIM  128
#define FF_   4096
#define B_    16
#define NSEQ  256
#define MTOK  4096          // B_*NSEQ
#define HID_  512
#define NFREQ 5997
#define K0_   11994         // 2*NFREQ

// ======================================================================
// Fourier angle embedding: h0[m][j] = cos(2pi*mz*b_j), h0[m][NF+j] = sin
// Bit-matches JAX op order: fl(2pi_f32 * fl(mz*b)).
// ======================================================================
__global__ __launch_bounds__(256)
void fourier_k(const float* __restrict__ spec, const float* __restrict__ fb,
               float* __restrict__ h0)
{
    int j = blockIdx.x * 256 + threadIdx.x;
    int m = blockIdx.y;
    if (j >= NFREQ) return;
    float mz  = spec[(size_t)m * 2];
    float ang = 6.2831853071795864769f * (mz * fb[j]);   // rounds to 0x40C90FDB
    float s, c;
    sincosf(ang, &s, &c);                                // precise (Payne-Hanek)
    size_t base = (size_t)m * K0_;
    h0[base + j]         = c;
    h0[base + NFREQ + j] = s;
}

// ======================================================================
// Peak embedding: x[m][DF_+n] = relu(mz*pw[n][0] + it*pw[n][1] + pb[n])
// ======================================================================
__global__ __launch_bounds__(64)
void peak_k(const float* __restrict__ spec, const float* __restrict__ pw,
            const float* __restrict__ pb, float* __restrict__ x)
{
    int m = blockIdx.x;
    int n = threadIdx.x;
    if (n >= DP_) return;
    float mz = spec[(size_t)m*2], it = spec[(size_t)m*2+1];
    float v = mz * pw[n*2] + it * pw[n*2+1] + pb[n];
    x[(size_t)m*DD_ + DF_ + n] = fmaxf(v, 0.f);
}

// ======================================================================
// GEMM (NT): C[m][n] = sum_k A[m][k]*W[n][k]  (+bias, +residual, relu)
// 64x64x16 tile, 4x4 micro, scalar global loads (handles any alignment,
// any N, any K). Used for the Fourier MLP (K=11994, N=980 cases).
// ======================================================================
template<bool RELU, bool RES>
__global__ __launch_bounds__(256)
void gemm64(const float* __restrict__ A, int lda,
            const float* __restrict__ W, int ldw,
            const float* __restrict__ bias,
            const float* __restrict__ resid, int ldres,
            float* __restrict__ C, int ldc,
            int N, int K)
{
    __shared__ float As[16][68];
    __shared__ float Bs[16][68];
    const int tid = threadIdx.x;
    const int bm = blockIdx.y * 64;
    const int bn = blockIdx.x * 64;
    const int lr = tid >> 2;          // 0..63 tile row
    const int lk = (tid & 3) * 4;     // k sub-offset 0,4,8,12
    const int tx = tid & 15, ty = tid >> 4;
    const float* Arow = A + (size_t)(bm + lr) * lda;
    const bool   wvalid = (bn + lr) < N;
    const float* Wrow = W + (size_t)(bn + lr) * ldw;

    float acc[4][4] = {};
    float av[4], wv[4];
    #pragma unroll
    for (int i = 0; i < 4; i++) {
        int k = lk + i;
        av[i] = (k < K) ? Arow[k] : 0.f;
        wv[i] = (wvalid && k < K) ? Wrow[k] : 0.f;
    }
    for (int k0 = 0; k0 < K; k0 += 16) {
        __syncthreads();
        #pragma unroll
        for (int i = 0; i < 4; i++) { As[lk+i][lr] = av[i]; Bs[lk+i][lr] = wv[i]; }
        __syncthreads();
        int kn = k0 + 16;
        if (kn < K) {                       // prefetch next tile during compute
            #pragma unroll
            for (int i = 0; i < 4; i++) {
                int k = kn + lk + i;
                av[i] = (k < K) ? Arow[k] : 0.f;
                wv[i] = (wvalid && k < K) ? Wrow[k] : 0.f;
            }
        }
        #pragma unroll
        for (int k = 0; k < 16; k++) {
            float a4[4], b4[4];
            *(float4*)a4 = *(const float4*)&As[k][ty*4];
            *(float4*)b4 = *(const float4*)&Bs[k][tx*4];
            #pragma unroll
            for (int i2 = 0; i2 < 4; i2++)
                #pragma unroll
                for (int j2 = 0; j2 < 4; j2++) acc[i2][j2] += a4[i2] * b4[j2];
        }
    }
    #pragma unroll
    for (int i2 = 0; i2 < 4; i2++) {
        size_t m = bm + ty*4 + i2;
        int nb = bn + tx*4;
        if (nb < N) {                       // N%4==0 for all our shapes
            float4 v;
            v.x = acc[i2][0]; v.y = acc[i2][1]; v.z = acc[i2][2]; v.w = acc[i2][3];
            if (bias) { v.x += bias[nb]; v.y += bias[nb+1]; v.z += bias[nb+2]; v.w += bias[nb+3]; }
            if (RES)  { const float4 r = *(const float4*)&resid[m*ldres + nb];
                        v.x += r.x; v.y += r.y; v.z += r.z; v.w += r.w; }
            if (RELU) { v.x = fmaxf(v.x,0.f); v.y = fmaxf(v.y,0.f);
                        v.z = fmaxf(v.z,0.f); v.w = fmaxf(v.w,0.f); }
            *(float4*)&C[m*ldc + nb] = v;
        }
    }
}

// ======================================================================
// GEMM (NT): 128x128x8 tile, 8x8 micro, float4 loads. Requires lda,ldw
// multiples of 4 and K multiple of 8 (true for all transformer GEMMs).
// ======================================================================
template<bool RELU, bool RES>
__global__ __launch_bounds__(256)
void gemm128(const float* __restrict__ A, int lda,
             const float* __restrict__ W, int ldw,
             const float* __restrict__ bias,
             const float* __restrict__ resid, int ldres,
             float* __restrict__ C, int ldc,
             int N, int K)
{
    __shared__ float As[8][132];
    __shared__ float Bs[8][132];
    const int tid = threadIdx.x;
    const int bm = blockIdx.y * 128;
    const int bn = blockIdx.x * 128;
    const int lr = tid >> 1;            // 0..127
    const int lk = (tid & 1) * 4;       // 0 or 4
    const int tx = tid & 15, ty = tid >> 4;
    const float* Arow = A + (size_t)(bm + lr) * lda + lk;
    const bool   wvalid = (bn + lr) < N;
    const float* Wrow = W + (size_t)(bn + lr) * ldw + lk;

    float acc[8][8] = {};
    float4 av = *(const float4*)(Arow);
    float4 wv = wvalid ? *(const float4*)(Wrow) : make_float4(0.f,0.f,0.f,0.f);

    for (int k0 = 0; k0 < K; k0 += 8) {
        __syncthreads();
        As[lk+0][lr]=av.x; As[lk+1][lr]=av.y; As[lk+2][lr]=av.z; As[lk+3][lr]=av.w;
        Bs[lk+0][lr]=wv.x; Bs[lk+1][lr]=wv.y; Bs[lk+2][lr]=wv.z; Bs[lk+3][lr]=wv.w;
        __syncthreads();
        int kn = k0 + 8;
        if (kn < K) {                       // prefetch overlaps compute
            av = *(const float4*)(Arow + kn);
            wv = wvalid ? *(const float4*)(Wrow + kn) : make_float4(0.f,0.f,0.f,0.f);
        }
        #pragma unroll
        for (int k = 0; k < 8; k++) {
            float a8[8], b8[8];
            *(float4*)&a8[0] = *(const float4*)&As[k][ty*8];
            *(float4*)&a8[4] = *(const float4*)&As[k][ty*8+4];
            *(float4*)&b8[0] = *(const float4*)&Bs[k][tx*8];
            *(float4*)&b8[4] = *(const float4*)&Bs[k][tx*8+4];
            #pragma unroll
            for (int i2 = 0; i2 < 8; i2++)
                #pragma unroll
                for (int j2 = 0; j2 < 8; j2++) acc[i2][j2] += a8[i2] * b8[j2];
        }
    }
    #pragma unroll
    for (int i2 = 0; i2 < 8; i2++) {
        size_t m = bm + ty*8 + i2;
        #pragma unroll
        for (int j2 = 0; j2 < 8; j2 += 4) {
            int n = bn + tx*8 + j2;
            if (n < N) {
                float4 v;
                v.x = acc[i2][j2+0]; v.y = acc[i2][j2+1];
                v.z = acc[i2][j2+2]; v.w = acc[i2][j2+3];
                if (bias) { v.x += bias[n]; v.y += bias[n+1]; v.z += bias[n+2]; v.w += bias[n+3]; }
                if (RES)  { const float4 r = *(const float4*)&resid[m*ldres + n];
                            v.x += r.x; v.y += r.y; v.z += r.z; v.w += r.w; }
                if (RELU) { v.x = fmaxf(v.x,0.f); v.y = fmaxf(v.y,0.f);
                            v.z = fmaxf(v.z,0.f); v.w = fmaxf(v.w,0.f); }
                *(float4*)&C[m*ldc + n] = v;
            }
        }
    }
}

// ======================================================================
// LayerNorm (two-pass, matches reference mean/var order). One block/row.
// ======================================================================
__device__ __forceinline__ float block_sum(float v, float* red, int tid)
{
    #pragma unroll
    for (int o = 32; o >= 1; o >>= 1) v += __shfl_xor(v, o, 64);
    if ((tid & 63) == 0) red[tid >> 6] = v;
    __syncthreads();
    float r = red[0] + red[1] + red[2] + red[3];
    __syncthreads();
    return r;
}

__global__ __launch_bounds__(256)
void ln_k(const float* __restrict__ x, const float* __restrict__ g,
          const float* __restrict__ bta, float* __restrict__ y)
{
    __shared__ float red[4];
    int m = blockIdx.x, tid = threadIdx.x;
    const float* xr = x + (size_t)m * DD_;
    float4 v = *(const float4*)&xr[tid*4];
    float mean = block_sum(v.x+v.y+v.z+v.w, red, tid) * (1.f/1024.f);
    float d0 = v.x-mean, d1 = v.y-mean, d2 = v.z-mean, d3 = v.w-mean;
    float var = block_sum(d0*d0+d1*d1+d2*d2+d3*d3, red, tid) * (1.f/1024.f);
    float inv = 1.0f / sqrtf(var + 1e-5f);
    float4 gg = *(const float4*)&g[tid*4];
    float4 bb = *(const float4*)&bta[tid*4];
    float4 o;
    o.x = d0*inv*gg.x + bb.x;  o.y = d1*inv*gg.y + bb.y;
    o.z = d2*inv*gg.z + bb.z;  o.w = d3*inv*gg.w + bb.w;
    *(float4*)&y[(size_t)m*DD_ + tid*4] = o;
}

// ======================================================================
// Attention scores: s[b,h,i,j] = scale*q.k + (mz_i - mz_j); mask -> -1e9
// 64x64 score tile per block; Q/K staged d-major in LDS.
// ======================================================================
__global__ __launch_bounds__(256)
void attn_scores(const float* __restrict__ qkv, const float* __restrict__ spec,
                 float* __restrict__ sout)
{
    __shared__ float Qs[HDIM][68];
    __shared__ float Ks[HDIM][68];
    const int tid = threadIdx.x;
    const int bh = blockIdx.z, b = bh >> 3, h = bh & 7;
    const int i0 = blockIdx.y * 64, j0 = blockIdx.x * 64;
    const int lr = tid >> 2, ld0 = (tid & 3) * 32;
    {
        const float* qp = qkv + (size_t)(b*NSEQ + i0 + lr)*(3*DD_) + h*HDIM + ld0;
        const float* kp = qkv + (size_t)(b*NSEQ + j0 + lr)*(3*DD_) + DD_ + h*HDIM + ld0;
        #pragma unroll
        for (int c = 0; c < 32; c += 4) {
            float4 qv = *(const float4*)(qp + c);
            float4 kv = *(const float4*)(kp + c);
            Qs[ld0+c+0][lr]=qv.x; Qs[ld0+c+1][lr]=qv.y; Qs[ld0+c+2][lr]=qv.z; Qs[ld0+c+3][lr]=qv.w;
            Ks[ld0+c+0][lr]=kv.x; Ks[ld0+c+1][lr]=kv.y; Ks[ld0+c+2][lr]=kv.z; Ks[ld0+c+3][lr]=kv.w;
        }
    }
    __syncthreads();
    const int tx = tid & 15, ty = tid >> 4;
    float acc[4][4] = {};
    #pragma unroll 4
    for (int d = 0; d < HDIM; d++) {
        float a4[4], b4[4];
        *(float4*)a4 = *(const float4*)&Qs[d][ty*4];
        *(float4*)b4 = *(const float4*)&Ks[d][tx*4];
        #pragma unroll
        for (int i2 = 0; i2 < 4; i2++)
            #pragma unroll
            for (int j2 = 0; j2 < 4; j2++) acc[i2][j2] += a4[i2] * b4[j2];
    }
    const float scale = 0.08838834764831845f;   // 128^-0.5
    float mzi[4], mzj[4], itj[4];
    #pragma unroll
    for (int i2 = 0; i2 < 4; i2++) mzi[i2] = spec[(size_t)(b*NSEQ + i0 + ty*4 + i2)*2];
    #pragma unroll
    for (int j2 = 0; j2 < 4; j2++) {
        size_t jj = (size_t)(b*NSEQ + j0 + tx*4 + j2)*2;
        mzj[j2] = spec[jj]; itj[j2] = spec[jj+1];
    }
    float* srow = sout + ((size_t)bh*NSEQ + i0)*NSEQ + j0;
    #pragma unroll
    for (int i2 = 0; i2 < 4; i2++)
        #pragma unroll
        for (int j2 = 0; j2 < 4; j2++) {
            float v = acc[i2][j2]*scale + (mzi[i2] - mzj[j2]);
            if (itj[j2] == 0.f) v = -1000000000.0f;
            srow[(size_t)(ty*4+i2)*NSEQ + tx*4 + j2] = v;
        }
}

// ======================================================================
// Row softmax over 256 cols, 1 wave per row, 4 rows per block.
// ======================================================================
__global__ __launch_bounds__(256)
void softmax_k(float* __restrict__ s)
{
    int row  = blockIdx.x*4 + (threadIdx.x >> 6);
    int lane = threadIdx.x & 63;
    float* sr = s + (size_t)row * NSEQ;
    float v0 = sr[lane], v1 = sr[lane+64], v2 = sr[lane+128], v3 = sr[lane+192];
    float mx = fmaxf(fmaxf(v0,v1), fmaxf(v2,v3));
    #pragma unroll
    for (int o = 32; o >= 1; o >>= 1) mx = fmaxf(mx, __shfl_xor(mx, o, 64));
    float e0 = expf(v0-mx), e1 = expf(v1-mx), e2 = expf(v2-mx), e3 = expf(v3-mx);
    float sm = e0+e1+e2+e3;
    #pragma unroll
    for (int o = 32; o >= 1; o >>= 1) sm += __shfl_xor(sm, o, 64);
    float r = 1.0f / sm;
    sr[lane] = e0*r; sr[lane+64] = e1*r; sr[lane+128] = e2*r; sr[lane+192] = e3*r;
}

// ======================================================================
// PV: o[b, i, h*128+d] = sum_j a[bh,i,j] * v[b,j,h,d]
// 32 rows per block; A-tile in LDS; V streamed (L1/L2-resident).
// ======================================================================
__global__ __launch_bounds__(256)
void attn_pv(const float* __restrict__ a, const float* __restrict__ qkv,
             float* __restrict__ o)
{
    __shared__ float As[32][NSEQ+1];
    const int tid = threadIdx.x;
    const int bh = blockIdx.y, b = bh >> 3, h = bh & 7;
    const int i0 = blockIdx.x * 32;
    {
        const int lr = tid >> 3, lc0 = (tid & 7) * 32;
        const float* ag = a + ((size_t)bh*NSEQ + i0 + lr)*NSEQ + lc0;
        #pragma unroll
        for (int c = 0; c < 32; c += 4) {
            float4 v = *(const float4*)(ag + c);
            As[lr][lc0+c+0]=v.x; As[lr][lc0+c+1]=v.y; As[lr][lc0+c+2]=v.z; As[lr][lc0+c+3]=v.w;
        }
    }
    __syncthreads();
    const int ii = tid >> 3, d0 = (tid & 7) * 16;
    const float* vbase = qkv + (size_t)b*NSEQ*3*DD_ + 2*DD_ + h*HDIM + d0;
    float acc[16] = {};
    for (int j = 0; j < NSEQ; j++) {
        float aval = As[ii][j];
        const float* vr = vbase + (size_t)j*3*DD_;
        float4 x0 = *(const float4*)(vr);
        float4 x1 = *(const float4*)(vr+4);
        float4 x2 = *(const float4*)(vr+8);
        float4 x3 = *(const float4*)(vr+12);
        acc[0]+=aval*x0.x; acc[1]+=aval*x0.y; acc[2]+=aval*x0.z; acc[3] +=aval*x0.w;
        acc[4]+=aval*x1.x; acc[5]+=aval*x1.y; acc[6] +=aval*x1.z; acc[7] +=aval*x1.w;
        acc[8]+=aval*x2.x; acc[9]+=aval*x2.y; acc[10]+=aval*x2.z; acc[11]+=aval*x2.w;
        acc[12]+=aval*x3.x; acc[13]+=aval*x3.y; acc[14]+=aval*x3.z; acc[15]+=aval*x3.w;
    }
    float* orow = o + (size_t)(b*NSEQ + i0 + ii)*DD_ + h*HDIM + d0;
    *(float4*)(orow)    = make_float4(acc[0],acc[1],acc[2],acc[3]);
    *(float4*)(orow+4)  = make_float4(acc[4],acc[5],acc[6],acc[7]);
    *(float4*)(orow+8)  = make_float4(acc[8],acc[9],acc[10],acc[11]);
    *(float4*)(orow+12) = make_float4(acc[12],acc[13],acc[14],acc[15]);
}

// ======================================================================
// Launch. ws layout (floats):
//  [0, 49127424)            h0   (4096 x 11994)   -- freed after GEMM0
//  [49127424, +2097152)     h1
//  [51224576, +2097152)     h2
//  [53321728, +4194304)     x
//  aliases over the h0 region (h0 dead by then):
//  y@0, qkv@4194304, s@16777216, o@25165824, ffnh@29360128 (end 46137344)
//  total ws need: 230,064,128 bytes
// ======================================================================
extern "C" void kernel_launch(void* const* d_in, const int* in_sizes, int n_in,
                              void* d_out, int out_size, void* d_ws, size_t ws_size,
                              hipStream_t stream)
{
    const float* spec = (const float*)d_in[0];
    const float* fb   = (const float*)d_in[1];
    const float* pw   = (const float*)d_in[2];
    const float* pb   = (const float*)d_in[3];
    const float* fw[5]    = {(const float*)d_in[4], (const float*)d_in[6],
                             (const float*)d_in[8], (const float*)d_in[10],
                             (const float*)d_in[12]};
    const float* fbias[5] = {(const float*)d_in[5], (const float*)d_in[7],
                             (const float*)d_in[9], (const float*)d_in[11],
                             (const float*)d_in[13]};
    const float* w_qkvo = (const float*)d_in[14];
    const float* ffn_w1 = (const float*)d_in[15];
    const float* ffn_w2 = (const float*)d_in[16];
    const float* ln1g = (const float*)d_in[17], *ln1b = (const float*)d_in[18];
    const float* ln2g = (const float*)d_in[19], *ln2b = (const float*)d_in[20];
    const float* lnfg = (const float*)d_in[21], *lnfb = (const float*)d_in[22];

    float* ws  = (float*)d_ws;
    float* h0  = ws;
    float* h1  = ws + 49127424;
    float* h2  = h1 + 2097152;
    float* x   = h2 + 2097152;
    float* y    = ws;
    float* qkv  = ws + 4194304;
    float* sbuf = ws + 16777216;
    float* obuf = ws + 25165824;
    float* ffnh = ws + 29360128;
    float* out = (float*)d_out;

    // Fourier features + MLP
    fourier_k<<<dim3(24, MTOK), 256, 0, stream>>>(spec, fb, h0);
    gemm64<true,false><<<dim3(8,64),256,0,stream>>>(h0, K0_, fw[0], K0_, fbias[0], nullptr,0, h1, HID_, HID_, K0_);
    gemm64<true,false><<<dim3(8,64),256,0,stream>>>(h1, HID_, fw[1], HID_, fbias[1], nullptr,0, h2, HID_, HID_, HID_);
    gemm64<true,false><<<dim3(8,64),256,0,stream>>>(h2, HID_, fw[2], HID_, fbias[2], nullptr,0, h1, HID_, HID_, HID_);
    gemm64<true,false><<<dim3(8,64),256,0,stream>>>(h1, HID_, fw[3], HID_, fbias[3], nullptr,0, h2, HID_, HID_, HID_);
    gemm64<true,false><<<dim3(16,64),256,0,stream>>>(h2, HID_, fw[4], HID_, fbias[4], nullptr,0, x, DD_, DF_, HID_);
    peak_k<<<dim3(MTOK), 64, 0, stream>>>(spec, pw, pb, x);

    // Transformer layers
    for (int i = 0; i < L_; i++) {
        const float* Wq = w_qkvo + (size_t)i*4*DD_*DD_;
        ln_k<<<MTOK,256,0,stream>>>(x, ln1g + i*DD_, ln1b + i*DD_, y);
        gemm128<false,false><<<dim3(24,32),256,0,stream>>>(y, DD_, Wq, DD_, nullptr, nullptr,0, qkv, 3*DD_, 3*DD_, DD_);
        attn_scores<<<dim3(4,4,B_*H_),256,0,stream>>>(qkv, spec, sbuf);
        softmax_k<<<dim3(B_*H_*NSEQ/4),256,0,stream>>>(sbuf);
        attn_pv<<<dim3(8,B_*H_),256,0,stream>>>(sbuf, qkv, obuf);
        gemm128<false,true><<<dim3(8,32),256,0,stream>>>(obuf, DD_, Wq + (size_t)3*DD_*DD_, DD_, nullptr, x, DD_, x, DD_, DD_, DD_);
        ln_k<<<MTOK,256,0,stream>>>(x, ln2g + i*DD_, ln2b + i*DD_, y);
        gemm128<true,false><<<dim3(32,32),256,0,stream>>>(y, DD_, ffn_w1 + (size_t)i*FF_*DD_, DD_, nullptr, nullptr,0, ffnh, FF_, FF_, DD_);
        gemm128<false,true><<<dim3(8,32),256,0,stream>>>(ffnh, FF_, ffn_w2 + (size_t)i*DD_*FF_, FF_, nullptr, x, DD_, x, DD_, DD_, FF_);
    }
    ln_k<<<MTOK,256,0,stream>>>(x, lnfg, lnfb, out);
}

// Round 2
// 5281.497 us; speedup vs baseline: 2.4462x; 2.4462x over previous
//
#include <hip/hip_runtime.h>
#include <hip/hip_bf16.h>
#include <math.h>

// ---- problem constants -------------------------------------------------
#define L_    7
#define H_    8
#define DF_   980
#define DP_   44
#define DD_   1024
#define HDIM  128
#define FF_   4096
#define B_    16
#define NSEQ  256
#define MTOK  4096          // B_*NSEQ
#define HID_  512
#define NFREQ 5997
#define KP0   12032         // 2*NFREQ=11994 padded to mult of 64

typedef __attribute__((ext_vector_type(8))) short short8_t;
typedef __attribute__((ext_vector_type(4))) float f32x4;

// ---- bf16 split helpers ------------------------------------------------
__device__ __forceinline__ unsigned short bf16_hi(float v) {
    __hip_bfloat16 b = __float2bfloat16(v);
    union { __hip_bfloat16 b; unsigned short u; } c; c.b = b; return c.u;
}
__device__ __forceinline__ float bf16_to_f(unsigned short u) {
    union { unsigned int x; float f; } c; c.x = ((unsigned int)u) << 16; return c.f;
}
__device__ __forceinline__ void bf16_split(float v, unsigned short& h, unsigned short& l) {
    h = bf16_hi(v);
    l = bf16_hi(v - bf16_to_f(h));
}

// async global->LDS, 16B per lane (wave-uniform LDS base + lane*16)
__device__ __forceinline__ void gl_lds16(const void* g, void* l) {
    __builtin_amdgcn_global_load_lds(
        (const __attribute__((address_space(1))) void*)g,
        (__attribute__((address_space(3))) void*)l, 16, 0, 0);
}

// ======================================================================
// Fourier features -> bf16 hi plane h0h [4096][KP0], zero-padded cols.
// ang matches JAX op order fl(2pi * fl(mz*b)); sincosf is precise.
// ======================================================================
__global__ __launch_bounds__(256)
void fourier_k(const float* __restrict__ spec, const float* __restrict__ fb,
               unsigned short* __restrict__ h0h)
{
    int j = blockIdx.x * 256 + threadIdx.x;   // grid.x=24 -> j<6144
    int m = blockIdx.y;
    if (j < NFREQ) {
        float mz  = spec[(size_t)m * 2];
        float ang = 6.2831853071795864769f * (mz * fb[j]);
        float s, c;
        sincosf(ang, &s, &c);
        size_t base = (size_t)m * KP0;
        h0h[base + j]         = bf16_hi(c);
        h0h[base + NFREQ + j] = bf16_hi(s);
    } else if (j + NFREQ < KP0) {             // zero pad cols 11994..12031
        h0h[(size_t)m * KP0 + j + NFREQ] = 0;
    }
}

// ======================================================================
// Peak embedding into x fp32 (cols DF_..DD_)
// ======================================================================
__global__ __launch_bounds__(64)
void peak_k(const float* __restrict__ spec, const float* __restrict__ pw,
            const float* __restrict__ pb, float* __restrict__ x)
{
    int m = blockIdx.x;
    int n = threadIdx.x;
    if (n >= DP_) return;
    float mz = spec[(size_t)m*2], it = spec[(size_t)m*2+1];
    float v = mz * pw[n*2] + it * pw[n*2+1] + pb[n];
    x[(size_t)m*DD_ + DF_ + n] = fmaxf(v, 0.f);
}

// ======================================================================
// fp32 weight [N][K] -> bf16 hi/lo planes [Npad][Kpad] (zero-padded)
// ======================================================================
__global__ __launch_bounds__(256)
void cvt_w(const float* __restrict__ W, unsigned short* __restrict__ hi,
           unsigned short* __restrict__ lo, int N, int K, int Npad, int Kpad)
{
    unsigned int total = (unsigned int)Npad * (unsigned int)Kpad;
    for (unsigned int idx = blockIdx.x*256u + threadIdx.x; idx < total;
         idx += gridDim.x * 256u) {
        float v;
        if (K == Kpad) {
            v = (idx < (unsigned int)N * (unsigned int)K) ? W[idx] : 0.f;
        } else {
            unsigned int n = idx / (unsigned int)Kpad, k = idx % (unsigned int)Kpad;
            v = (n < (unsigned int)N && k < (unsigned int)K) ? W[(size_t)n*K + k] : 0.f;
        }
        unsigned short h, l2; bf16_split(v, h, l2);
        hi[idx] = h; lo[idx] = l2;
    }
}

// ======================================================================
// Split-precision MFMA GEMM (NT): C[m][n] = sum_k A[m][k]*W[n][k]
//   A = Ah + Al (bf16 planes), B = Bh + Bl;  C ~= AhBh + AlBh + AhBl
// 128x128 tile, BK=64, global_load_lds(16B) with pre-swizzled source,
// XOR-swizzled ds_read_b128 (byte ^= (row&7)<<4 within 128B rows).
// M fixed 4096; K mult of 64; B buffer padded to Npad=128*gridDim.x.
// ======================================================================
template<bool ALO, bool BIAS, bool RELU, bool RES, bool OUTPL>
__global__ __launch_bounds__(256)
void mgemm(const unsigned short* __restrict__ Ah, const unsigned short* __restrict__ Al,
           const unsigned short* __restrict__ Bh, const unsigned short* __restrict__ Bl,
           const float* __restrict__ bias,
           const float* __restrict__ resid, int ldres,
           float* __restrict__ Cf, unsigned short* __restrict__ Ch,
           unsigned short* __restrict__ Cl,
           int ldc, int N, int K)
{
    constexpr int NPL = ALO ? 4 : 3;
    __shared__ __align__(16) unsigned short lds[NPL * 8192];
    const int tid = threadIdx.x;
    const int bm = blockIdx.y * 128, bn = blockIdx.x * 128;

    // ---- staging addresses (pre-swizzled source slot) ----
    const int r0 = tid >> 3;                  // 0..31 (row mod 32 of tile)
    const int ss = (tid & 7) ^ (r0 & 7);      // source 16B slot
    const unsigned short* gAh = Ah + (size_t)(bm + r0) * K + ss * 8;
    const unsigned short* gBh = Bh + (size_t)(bn + r0) * K + ss * 8;
    const unsigned short* gBl = Bl + (size_t)(bn + r0) * K + ss * 8;
    const unsigned short* gAl = nullptr;
    if constexpr (ALO) gAl = Al + (size_t)(bm + r0) * K + ss * 8;

    unsigned short* ldsA  = lds;
    unsigned short* ldsBh = lds + 8192;
    unsigned short* ldsBl = lds + 16384;
    unsigned short* ldsAl = lds + 24576;      // only if ALO

    const int l = tid & 63, wid = tid >> 6;
    const int wr = wid >> 1, wc = wid & 1;    // wave -> 64x64 quadrant
    const int lrow = l & 15, sidx = l >> 4;
    const int x7 = lrow & 7;                  // swizzle key (row&7)

    f32x4 acc[4][4];
    #pragma unroll
    for (int i = 0; i < 4; i++)
        #pragma unroll
        for (int j = 0; j < 4; j++) acc[i][j] = (f32x4){0.f,0.f,0.f,0.f};

    for (int k0 = 0; k0 < K; k0 += 64) {
        __syncthreads();
        #pragma unroll
        for (int it = 0; it < 4; it++) {
            size_t go = (size_t)it * 32 * K + k0;
            int lo = it * 2048 + tid * 8;
            gl_lds16(gAh + go, ldsA  + lo);
            gl_lds16(gBh + go, ldsBh + lo);
            gl_lds16(gBl + go, ldsBl + lo);
            if constexpr (ALO) gl_lds16(gAl + go, ldsAl + lo);
        }
        __syncthreads();
        #pragma unroll
        for (int kk = 0; kk < 2; kk++) {
            const int sl = ((kk << 2) | sidx) ^ x7;
            short8_t bh[4], bl[4];
            #pragma unroll
            for (int ni = 0; ni < 4; ni++) {
                int rb = wc*64 + ni*16 + lrow;
                int byo = rb*128 + sl*16;
                bh[ni] = *(const short8_t*)((const char*)ldsBh + byo);
                bl[ni] = *(const short8_t*)((const char*)ldsBl + byo);
            }
            #pragma unroll
            for (int mi = 0; mi < 4; mi++) {
                int ra = wr*64 + mi*16 + lrow;
                int byo = ra*128 + sl*16;
                short8_t ah = *(const short8_t*)((const char*)ldsA + byo);
                short8_t al;
                if constexpr (ALO) al = *(const short8_t*)((const char*)ldsAl + byo);
                #pragma unroll
                for (int ni = 0; ni < 4; ni++) {
                    acc[mi][ni] = __builtin_amdgcn_mfma_f32_16x16x32_bf16(ah, bh[ni], acc[mi][ni], 0, 0, 0);
                    if constexpr (ALO)
                        acc[mi][ni] = __builtin_amdgcn_mfma_f32_16x16x32_bf16(al, bh[ni], acc[mi][ni], 0, 0, 0);
                    acc[mi][ni] = __builtin_amdgcn_mfma_f32_16x16x32_bf16(ah, bl[ni], acc[mi][ni], 0, 0, 0);
                }
            }
        }
    }

    // ---- epilogue: C/D layout col=lane&15, row=(lane>>4)*4+q ----
    #pragma unroll
    for (int mi = 0; mi < 4; mi++) {
        #pragma unroll
        for (int ni = 0; ni < 4; ni++) {
            int n = bn + wc*64 + ni*16 + lrow;
            if (n < N) {
                #pragma unroll
                for (int q = 0; q < 4; q++) {
                    int m = bm + wr*64 + mi*16 + (sidx<<2) + q;
                    float v = acc[mi][ni][q];
                    if constexpr (BIAS) v += bias[n];
                    if constexpr (RES)  v += resid[(size_t)m*ldres + n];
                    if constexpr (RELU) v = fmaxf(v, 0.f);
                    if constexpr (OUTPL) {
                        unsigned short h, l2; bf16_split(v, h, l2);
                        Ch[(size_t)m*ldc + n] = h;
                        Cl[(size_t)m*ldc + n] = l2;
                    } else {
                        Cf[(size_t)m*ldc + n] = v;
                    }
                }
            }
        }
    }
}

// ======================================================================
// LayerNorm helpers
// ======================================================================
__device__ __forceinline__ float block_sum(float v, float* red, int tid)
{
    #pragma unroll
    for (int o = 32; o >= 1; o >>= 1) v += __shfl_xor(v, o, 64);
    if ((tid & 63) == 0) red[tid >> 6] = v;
    __syncthreads();
    float r = red[0] + red[1] + red[2] + red[3];
    __syncthreads();
    return r;
}

__global__ __launch_bounds__(256)
void ln_k(const float* __restrict__ x, const float* __restrict__ g,
          const float* __restrict__ bta, float* __restrict__ y)
{
    __shared__ float red[4];
    int m = blockIdx.x, tid = threadIdx.x;
    const float* xr = x + (size_t)m * DD_;
    float4 v = *(const float4*)&xr[tid*4];
    float mean = block_sum(v.x+v.y+v.z+v.w, red, tid) * (1.f/1024.f);
    float d0 = v.x-mean, d1 = v.y-mean, d2 = v.z-mean, d3 = v.w-mean;
    float var = block_sum(d0*d0+d1*d1+d2*d2+d3*d3, red, tid) * (1.f/1024.f);
    float inv = 1.0f / sqrtf(var + 1e-5f);
    float4 gg = *(const float4*)&g[tid*4];
    float4 bb = *(const float4*)&bta[tid*4];
    float4 o;
    o.x = d0*inv*gg.x + bb.x;  o.y = d1*inv*gg.y + bb.y;
    o.z = d2*inv*gg.z + bb.z;  o.w = d3*inv*gg.w + bb.w;
    *(float4*)&y[(size_t)m*DD_ + tid*4] = o;
}

__global__ __launch_bounds__(256)
void ln_planes(const float* __restrict__ x, const float* __restrict__ g,
               const float* __restrict__ bta,
               unsigned short* __restrict__ yh, unsigned short* __restrict__ yl)
{
    __shared__ float red[4];
    int m = blockIdx.x, tid = threadIdx.x;
    const float* xr = x + (size_t)m * DD_;
    float4 v = *(const float4*)&xr[tid*4];
    float mean = block_sum(v.x+v.y+v.z+v.w, red, tid) * (1.f/1024.f);
    float d0 = v.x-mean, d1 = v.y-mean, d2 = v.z-mean, d3 = v.w-mean;
    float var = block_sum(d0*d0+d1*d1+d2*d2+d3*d3, red, tid) * (1.f/1024.f);
    float inv = 1.0f / sqrtf(var + 1e-5f);
    float4 gg = *(const float4*)&g[tid*4];
    float4 bb = *(const float4*)&bta[tid*4];
    float o0 = d0*inv*gg.x + bb.x, o1 = d1*inv*gg.y + bb.y;
    float o2 = d2*inv*gg.z + bb.z, o3 = d3*inv*gg.w + bb.w;
    size_t base = (size_t)m*DD_ + tid*4;
    unsigned short h, l2;
    bf16_split(o0, h, l2); yh[base+0] = h; yl[base+0] = l2;
    bf16_split(o1, h, l2); yh[base+1] = h; yl[base+1] = l2;
    bf16_split(o2, h, l2); yh[base+2] = h; yl[base+2] = l2;
    bf16_split(o3, h, l2); yh[base+3] = h; yl[base+3] = l2;
}

// ======================================================================
// Attention (fp32, unchanged math from R1)
// ======================================================================
__global__ __launch_bounds__(256)
void attn_scores(const float* __restrict__ qkv, const float* __restrict__ spec,
                 float* __restrict__ sout)
{
    __shared__ float Qs[HDIM][68];
    __shared__ float Ks[HDIM][68];
    const int tid = threadIdx.x;
    const int bh = blockIdx.z, b = bh >> 3, h = bh & 7;
    const int i0 = blockIdx.y * 64, j0 = blockIdx.x * 64;
    const int lr = tid >> 2, ld0 = (tid & 3) * 32;
    {
        const float* qp = qkv + (size_t)(b*NSEQ + i0 + lr)*(3*DD_) + h*HDIM + ld0;
        const float* kp = qkv + (size_t)(b*NSEQ + j0 + lr)*(3*DD_) + DD_ + h*HDIM + ld0;
        #pragma unroll
        for (int c = 0; c < 32; c += 4) {
            float4 qv = *(const float4*)(qp + c);
            float4 kv = *(const float4*)(kp + c);
            Qs[ld0+c+0][lr]=qv.x; Qs[ld0+c+1][lr]=qv.y; Qs[ld0+c+2][lr]=qv.z; Qs[ld0+c+3][lr]=qv.w;
            Ks[ld0+c+0][lr]=kv.x; Ks[ld0+c+1][lr]=kv.y; Ks[ld0+c+2][lr]=kv.z; Ks[ld0+c+3][lr]=kv.w;
        }
    }
    __syncthreads();
    const int tx = tid & 15, ty = tid >> 4;
    float acc[4][4] = {};
    #pragma unroll 4
    for (int d = 0; d < HDIM; d++) {
        float a4[4], b4[4];
        *(float4*)a4 = *(const float4*)&Qs[d][ty*4];
        *(float4*)b4 = *(const float4*)&Ks[d][tx*4];
        #pragma unroll
        for (int i2 = 0; i2 < 4; i2++)
            #pragma unroll
            for (int j2 = 0; j2 < 4; j2++) acc[i2][j2] += a4[i2] * b4[j2];
    }
    const float scale = 0.08838834764831845f;   // 128^-0.5
    float mzi[4], mzj[4], itj[4];
    #pragma unroll
    for (int i2 = 0; i2 < 4; i2++) mzi[i2] = spec[(size_t)(b*NSEQ + i0 + ty*4 + i2)*2];
    #pragma unroll
    for (int j2 = 0; j2 < 4; j2++) {
        size_t jj = (size_t)(b*NSEQ + j0 + tx*4 + j2)*2;
        mzj[j2] = spec[jj]; itj[j2] = spec[jj+1];
    }
    float* srow = sout + ((size_t)bh*NSEQ + i0)*NSEQ + j0;
    #pragma unroll
    for (int i2 = 0; i2 < 4; i2++)
        #pragma unroll
        for (int j2 = 0; j2 < 4; j2++) {
            float v = acc[i2][j2]*scale + (mzi[i2] - mzj[j2]);
            if (itj[j2] == 0.f) v = -1000000000.0f;
            srow[(size_t)(ty*4+i2)*NSEQ + tx*4 + j2] = v;
        }
}

__global__ __launch_bounds__(256)
void softmax_k(float* __restrict__ s)
{
    int row  = blockIdx.x*4 + (threadIdx.x >> 6);
    int lane = threadIdx.x & 63;
    float* sr = s + (size_t)row * NSEQ;
    float v0 = sr[lane], v1 = sr[lane+64], v2 = sr[lane+128], v3 = sr[lane+192];
    float mx = fmaxf(fmaxf(v0,v1), fmaxf(v2,v3));
    #pragma unroll
    for (int o = 32; o >= 1; o >>= 1) mx = fmaxf(mx, __shfl_xor(mx, o, 64));
    float e0 = expf(v0-mx), e1 = expf(v1-mx), e2 = expf(v2-mx), e3 = expf(v3-mx);
    float sm = e0+e1+e2+e3;
    #pragma unroll
    for (int o = 32; o >= 1; o >>= 1) sm += __shfl_xor(sm, o, 64);
    float r = 1.0f / sm;
    sr[lane] = e0*r; sr[lane+64] = e1*r; sr[lane+128] = e2*r; sr[lane+192] = e3*r;
}

// PV -> bf16 hi/lo planes [4096][1024]
__global__ __launch_bounds__(256)
void attn_pv(const float* __restrict__ a, const float* __restrict__ qkv,
             unsigned short* __restrict__ oh, unsigned short* __restrict__ ol)
{
    __shared__ float As[32][NSEQ+1];
    const int tid = threadIdx.x;
    const int bh = blockIdx.y, b = bh >> 3, h = bh & 7;
    const int i0 = blockIdx.x * 32;
    {
        const int lr = tid >> 3, lc0 = (tid & 7) * 32;
        const float* ag = a + ((size_t)bh*NSEQ + i0 + lr)*NSEQ + lc0;
        #pragma unroll
        for (int c = 0; c < 32; c += 4) {
            float4 v = *(const float4*)(ag + c);
            As[lr][lc0+c+0]=v.x; As[lr][lc0+c+1]=v.y; As[lr][lc0+c+2]=v.z; As[lr][lc0+c+3]=v.w;
        }
    }
    __syncthreads();
    const int ii = tid >> 3, d0 = (tid & 7) * 16;
    const float* vbase = qkv + (size_t)b*NSEQ*3*DD_ + 2*DD_ + h*HDIM + d0;
    float acc[16] = {};
    for (int j = 0; j < NSEQ; j++) {
        float aval = As[ii][j];
        const float* vr = vbase + (size_t)j*3*DD_;
        float4 x0 = *(const float4*)(vr);
        float4 x1 = *(const float4*)(vr+4);
        float4 x2 = *(const float4*)(vr+8);
        float4 x3 = *(const float4*)(vr+12);
        acc[0]+=aval*x0.x; acc[1]+=aval*x0.y; acc[2]+=aval*x0.z; acc[3] +=aval*x0.w;
        acc[4]+=aval*x1.x; acc[5]+=aval*x1.y; acc[6] +=aval*x1.z; acc[7] +=aval*x1.w;
        acc[8]+=aval*x2.x; acc[9]+=aval*x2.y; acc[10]+=aval*x2.z; acc[11]+=aval*x2.w;
        acc[12]+=aval*x3.x; acc[13]+=aval*x3.y; acc[14]+=aval*x3.z; acc[15]+=aval*x3.w;
    }
    size_t base = (size_t)(b*NSEQ + i0 + ii)*DD_ + h*HDIM + d0;
    #pragma unroll
    for (int t = 0; t < 16; t++) {
        unsigned short h2, l2; bf16_split(acc[t], h2, l2);
        oh[base + t] = h2; ol[base + t] = l2;
    }
}

// ======================================================================
// Launch.  ws layout (313.0 MB total):
//  ushort region:
//   h0h      49,283,072  (4096xKP0; reused as FFN-hidden planes Hph/Hpl)
//   fw0 h/lo 12,320,768   fw1-3 h/lo 1,572,864   fw4 h/lo 1,048,576
//   P1 h/lo   8,388,608   P2 h/lo    8,388,608
//   wq h/lo   8,388,608   wf1 h/lo   8,388,608   wf2 h/lo 8,388,608
//  float region:
//   x 4,194,304   qkv 12,582,912   sbuf 8,388,608
// ======================================================================
extern "C" void kernel_launch(void* const* d_in, const int* in_sizes, int n_in,
                              void* d_out, int out_size, void* d_ws, size_t ws_size,
                              hipStream_t stream)
{
    const float* spec = (const float*)d_in[0];
    const float* fb   = (const float*)d_in[1];
    const float* pw   = (const float*)d_in[2];
    const float* pb   = (const float*)d_in[3];
    const float* fw[5]    = {(const float*)d_in[4], (const float*)d_in[6],
                             (const float*)d_in[8], (const float*)d_in[10],
                             (const float*)d_in[12]};
    const float* fbias[5] = {(const float*)d_in[5], (const float*)d_in[7],
                             (const float*)d_in[9], (const float*)d_in[11],
                             (const float*)d_in[13]};
    const float* w_qkvo = (const float*)d_in[14];
    const float* ffn_w1 = (const float*)d_in[15];
    const float* ffn_w2 = (const float*)d_in[16];
    const float* ln1g = (const float*)d_in[17], *ln1b = (const float*)d_in[18];
    const float* ln2g = (const float*)d_in[19], *ln2b = (const float*)d_in[20];
    const float* lnfg = (const float*)d_in[21], *lnfb = (const float*)d_in[22];
    float* out = (float*)d_out;

    unsigned short* p = (unsigned short*)d_ws;
    unsigned short* h0h = p;                 p += 49283072;
    unsigned short* Hph = h0h;                               // alias (h0h dead)
    unsigned short* Hpl = h0h + 16777216;
    unsigned short* fw0h = p;                p += 6160384;
    unsigned short* fw0l = p;                p += 6160384;
    unsigned short* fwkh[3], *fwkl[3];
    for (int i = 0; i < 3; i++) { fwkh[i] = p; p += 262144; fwkl[i] = p; p += 262144; }
    unsigned short* fw4h = p;                p += 524288;
    unsigned short* fw4l = p;                p += 524288;
    unsigned short* P1h = p;                 p += 4194304;
    unsigned short* P1l = p;                 p += 4194304;
    unsigned short* P2h = p;                 p += 4194304;
    unsigned short* P2l = p;                 p += 4194304;
    unsigned short* wqh = p;                 p += 4194304;
    unsigned short* wql = p;                 p += 4194304;
    unsigned short* wf1h = p;                p += 4194304;
    unsigned short* wf1l = p;                p += 4194304;
    unsigned short* wf2h = p;                p += 4194304;
    unsigned short* wf2l = p;                p += 4194304;
    float* fx   = (float*)p;
    float* x    = fx;                        fx += 4194304;
    float* qkv  = fx;                        fx += 12582912;
    float* sbuf = fx;                        fx += 8388608;

    // ---- Fourier weights -> planes (once per call) ----
    cvt_w<<<8192, 256, 0, stream>>>(fw[0], fw0h, fw0l, 512, 11994, 512, KP0);
    for (int i = 0; i < 3; i++)
        cvt_w<<<1024, 256, 0, stream>>>(fw[1+i], fwkh[i], fwkl[i], 512, 512, 512, 512);
    cvt_w<<<2048, 256, 0, stream>>>(fw[4], fw4h, fw4l, 980, 512, 1024, 512);

    // ---- Fourier features + MLP (MFMA) ----
    fourier_k<<<dim3(24, MTOK), 256, 0, stream>>>(spec, fb, h0h);
    mgemm<false,true,true,false,true><<<dim3(4,32),256,0,stream>>>(
        h0h, nullptr, fw0h, fw0l, fbias[0], nullptr,0, nullptr, P1h, P1l, 512, 512, KP0);
    mgemm<true,true,true,false,true><<<dim3(4,32),256,0,stream>>>(
        P1h, P1l, fwkh[0], fwkl[0], fbias[1], nullptr,0, nullptr, P2h, P2l, 512, 512, 512);
    mgemm<true,true,true,false,true><<<dim3(4,32),256,0,stream>>>(
        P2h, P2l, fwkh[1], fwkl[1], fbias[2], nullptr,0, nullptr, P1h, P1l, 512, 512, 512);
    mgemm<true,true,true,false,true><<<dim3(4,32),256,0,stream>>>(
        P1h, P1l, fwkh[2], fwkl[2], fbias[3], nullptr,0, nullptr, P2h, P2l, 512, 512, 512);
    mgemm<true,true,true,false,false><<<dim3(8,32),256,0,stream>>>(
        P2h, P2l, fw4h, fw4l, fbias[4], nullptr,0, x, nullptr, nullptr, DD_, DF_, 512);
    peak_k<<<dim3(MTOK), 64, 0, stream>>>(spec, pw, pb, x);

    // ---- Transformer layers ----
    for (int i = 0; i < L_; i++) {
        const float* Wq = w_qkvo + (size_t)i*4*DD_*DD_;
        cvt_w<<<16384,256,0,stream>>>(Wq, wqh, wql, 4096, 1024, 4096, 1024);
        ln_planes<<<MTOK,256,0,stream>>>(x, ln1g + i*DD_, ln1b + i*DD_, P1h, P1l);
        mgemm<true,false,false,false,false><<<dim3(24,32),256,0,stream>>>(
            P1h, P1l, wqh, wql, nullptr, nullptr,0, qkv, nullptr, nullptr, 3*DD_, 3*DD_, DD_);
        attn_scores<<<dim3(4,4,B_*H_),256,0,stream>>>(qkv, spec, sbuf);
        softmax_k<<<dim3(B_*H_*NSEQ/4),256,0,stream>>>(sbuf);
        attn_pv<<<dim3(8,B_*H_),256,0,stream>>>(sbuf, qkv, P2h, P2l);
        mgemm<true,false,false,true,false><<<dim3(8,32),256,0,stream>>>(
            P2h, P2l, wqh + (size_t)3072*1024, wql + (size_t)3072*1024, nullptr,
            x, DD_, x, nullptr, nullptr, DD_, DD_, DD_);
        cvt_w<<<16384,256,0,stream>>>(ffn_w1 + (size_t)i*FF_*DD_, wf1h, wf1l, 4096, 1024, 4096, 1024);
        ln_planes<<<MTOK,256,0,stream>>>(x, ln2g + i*DD_, ln2b + i*DD_, P1h, P1l);
        mgemm<true,false,true,false,true><<<dim3(32,32),256,0,stream>>>(
            P1h, P1l, wf1h, wf1l, nullptr, nullptr,0, nullptr, Hph, Hpl, FF_, FF_, DD_);
        cvt_w<<<16384,256,0,stream>>>(ffn_w2 + (size_t)i*DD_*FF_, wf2h, wf2l, 1024, 4096, 1024, 4096);
        mgemm<true,false,false,true,false><<<dim3(8,32),256,0,stream>>>(
            Hph, Hpl, wf2h, wf2l, nullptr, x, DD_, x, nullptr, nullptr, DD_, DD_, FF_);
    }
    ln_k<<<MTOK,256,0,stream>>>(x, lnfg, lnfb, out);
}